// Round 9
// baseline (283.774 us; speedup 1.0000x reference)
//
#include <hip/hip_runtime.h>
#include <hip/hip_bf16.h>

typedef short short8 __attribute__((ext_vector_type(8)));
typedef float f32x4 __attribute__((ext_vector_type(4)));
typedef unsigned short u16;

#define SCALE_C 0.17677669529663687f

__device__ __forceinline__ u16 f2b(float f) {
  union { float f; unsigned int u; } v; v.f = f;
  unsigned int u = v.u;
  return (u16)((u + 0x7FFFu + ((u >> 16) & 1u)) >> 16);
}
__device__ __forceinline__ float b2f(u16 b) {
  union { unsigned int u; float f; } v; v.u = ((unsigned int)b) << 16; return v.f;
}
__device__ __forceinline__ unsigned int cvtpk(float lo, float hi) {
  unsigned int r;
  asm("v_cvt_pk_bf16_f32 %0, %1, %2" : "=v"(r) : "v"(lo), "v"(hi));
  return r;
}
__device__ __forceinline__ void glds16(const void* g, void* l) {
  __builtin_amdgcn_global_load_lds(
      (const __attribute__((address_space(1))) unsigned int*)g,
      (__attribute__((address_space(3))) unsigned int*)l, 16, 0, 0);
}

// ---------------- prep (fused): weight transposes + Wtlo + biases ----------------
__global__ void prep01(const float* Wq, const float* Wk, const float* Wv, const float* Wo,
                       const float* bk, const float* bv, const float* Wt,
                       const float* bt, const float* bo,
                       u16* wqT, u16* wkvT, u16* woT, float* bkv,
                       float* wtloT, float* btlo) {
  int j = blockIdx.x, t = threadIdx.x;
  wqT[j * 256 + t] = f2b(Wq[t * 256 + j]);
  wkvT[j * 256 + t] = f2b(Wk[t * 256 + j]);
  wkvT[(256 + j) * 256 + t] = f2b(Wv[t * 256 + j]);
  woT[j * 256 + t] = f2b(Wo[t * 256 + j]);
  if (t == 0) { bkv[j] = bk[j]; bkv[256 + j] = bv[j]; }
  __shared__ float woj[256];
  woj[t] = Wo[t * 256 + j];
  __syncthreads();
  float s = 0.f;
  const float* wr = Wt + t * 256;
#pragma unroll 8
  for (int u = 0; u < 256; ++u) s += wr[u] * woj[u];
  wtloT[j * 256 + t] = s;  // = Wtlo[t][j]
  if (t == 0) {
    float b = bo[j];
    for (int u = 0; u < 256; ++u) b += bt[u] * woj[u];
    btlo[j] = b;
  }
}

__global__ void prep2(const float* pk, const float* wtloT, const u16* woT, u16* B5) {
  int n = blockIdx.x >> 8, j = blockIdx.x & 255, t = threadIdx.x;
  u16* r = B5 + ((size_t)(n * 256 + j)) * 512;
  r[t] = f2b(pk[n * 256 + t] * wtloT[j * 256 + t]);
  r[256 + t] = woT[j * 256 + t];
}

// ---------------- weight-stationary GEMM ----------------
// Block = 64 rows x 256 cols (full N), 4 waves (2M x 2N), wave tile 32x128.
// B: LDS [256 colrows][64 bf16] (128B rows, 8x16B granules), XOR g^(row&7) via
//    pre-swizzled GLOBAL source, glds dest linear, reads swizzled (proven r3/r8).
// A: straight global->VGPR fragments (fp32 + cvt_pk for MODE 0/1; bf16 MODE 2).
// MODE 0: q = x_q @ Wq + bq        -> q_ws (bf16, LDS-restaged stores)
// MODE 1: [k|v] = x_kv @ [Wk|Wv]   -> k_ws / v_ws (col-half per block)
// MODE 2: out = [v;q] @ B5(n) + btlo -> fp32 d_out (K=512 dual-A)
template <int MODE>
__global__ __launch_bounds__(256) void gemmW(
    const float* Af, const u16* Ab0, const u16* Ab1, const u16* Bw,
    const float* bias, u16* outk, u16* outv, float* outf) {
  __shared__ __align__(16) u16 Bs[256 * 64];  // 32KB; reused as C-tile in epilogue
  constexpr int KT = (MODE == 2) ? 8 : 4;
  constexpr int NWG = (MODE == 1) ? 2048 : 1024;
  constexpr int LDB = (MODE == 2) ? 512 : 256;
  int bid = blockIdx.x;
  int logical = (bid & 7) * (NWG >> 3) + (bid >> 3);  // XCD-chunked (NWG%8==0)
  int m0, colh = 0;
  const u16* Bp;
  const float* bs;
  if constexpr (MODE == 1) {
    colh = logical & 1;
    m0 = (logical >> 1) * 64;
    Bp = Bw + colh * 256 * 256;
    bs = bias + colh * 256;
  } else if constexpr (MODE == 0) {
    m0 = logical * 64; Bp = Bw; bs = bias;
  } else {
    m0 = logical * 64;
    Bp = Bw + (size_t)(m0 >> 12) * 131072;  // per-n B5 slab
    bs = bias;
  }
  int tid = threadIdx.x, lane = tid & 63, w = tid >> 6;
  int wm = w >> 1, wn = w & 1, rla = lane & 15, hi = lane >> 4;
  int grow = w * 8 + (lane >> 3);     // staging row low bits; (grow&7)==(lane>>3)
  int gsg = (lane & 7) ^ (lane >> 3); // inverse-swizzled source granule

  f32x4 acc[2][8];
#pragma unroll
  for (int i = 0; i < 2; ++i)
#pragma unroll
    for (int j = 0; j < 8; ++j) acc[i][j] = (f32x4){0.f, 0.f, 0.f, 0.f};

  for (int kt = 0; kt < KT; ++kt) {
    // ---- stage B: 256 colrows x 64 k (32KB), 8 glds/thread ----
#pragma unroll
    for (int p = 0; p < 8; ++p) {
      int r = p * 32 + grow;
      glds16(Bp + (size_t)r * LDB + kt * 64 + gsg * 8,
             (char*)Bs + (p * 32 + w * 8) * 128 + lane * 16);
    }
    // ---- A fragments straight from global ----
    short8 af[2][2];
#pragma unroll
    for (int i = 0; i < 2; ++i)
#pragma unroll
      for (int kk = 0; kk < 2; ++kk) {
        int row = m0 + wm * 32 + i * 16 + rla;
        if constexpr (MODE != 2) {
          const float* pa = Af + (size_t)row * 256 + kt * 64 + kk * 32 + hi * 8;
          f32x4 x = *(const f32x4*)pa;
          f32x4 y = *(const f32x4*)(pa + 4);
          unsigned int* op = (unsigned int*)&af[i][kk];
          op[0] = cvtpk(x[0], x[1]); op[1] = cvtpk(x[2], x[3]);
          op[2] = cvtpk(y[0], y[1]); op[3] = cvtpk(y[2], y[3]);
        } else {
          const u16* Ak = (kt < 4) ? Ab0 : Ab1;
          int koff = (kt & 3) * 64;
          af[i][kk] = *(const short8*)(Ak + (size_t)row * 256 + koff + kk * 32 + hi * 8);
        }
      }
    __syncthreads();  // drains glds (vmcnt) before reads
    // ---- compute: 2 kk-halves x 2 row-frags x 8 col-frags ----
#pragma unroll
    for (int kk = 0; kk < 2; ++kk) {
      short8 bf[8];
#pragma unroll
      for (int j = 0; j < 8; ++j) {
        int rb = wn * 128 + j * 16 + rla;
        int gd = kk * 4 + hi;
        bf[j] = *(const short8*)((char*)Bs + rb * 128 + ((gd ^ (rb & 7)) << 4));
      }
#pragma unroll
      for (int i = 0; i < 2; ++i)
#pragma unroll
        for (int j = 0; j < 8; ++j)
          acc[i][j] = __builtin_amdgcn_mfma_f32_16x16x32_bf16(af[i][kk], bf[j], acc[i][j], 0, 0, 0);
    }
    __syncthreads();
  }

  // ---- epilogue ----
  if constexpr (MODE == 2) {
#pragma unroll
    for (int i = 0; i < 2; ++i)
#pragma unroll
      for (int j = 0; j < 8; ++j) {
        int col = wn * 128 + j * 16 + rla;
        float bb = bs[col];
#pragma unroll
        for (int e = 0; e < 4; ++e) {
          int row = m0 + wm * 32 + i * 16 + hi * 4 + e;
          outf[(size_t)row * 256 + col] = acc[i][j][e] + bb;
        }
      }
  } else {
    // restage C (64 rows x 256 cols bf16 = 32KB, swizzled 512B rows) into Bs
    char* sC = (char*)Bs;
#pragma unroll
    for (int i = 0; i < 2; ++i)
#pragma unroll
      for (int j = 0; j < 8; ++j) {
        int c = wn * 128 + j * 16 + rla;
        float bb = bs[c];
        int g = c >> 3;
#pragma unroll
        for (int e = 0; e < 4; ++e) {
          int r = wm * 32 + i * 16 + hi * 4 + e;
          int lg = (g & 0x18) | ((g & 7) ^ (r & 7));
          *(u16*)(sC + r * 512 + lg * 16 + (c & 7) * 2) = f2b(acc[i][j][e] + bb);
        }
      }
    __syncthreads();
    u16* outp = (MODE == 1 && colh) ? outv : outk;
    int r = tid >> 2, seg = tid & 3;
#pragma unroll
    for (int i = 0; i < 8; ++i) {
      int g2 = seg * 8 + i;
      int lg = (g2 & 0x18) | ((g2 & 7) ^ (r & 7));
      short8 vv = *(const short8*)(sC + r * 512 + lg * 16);
      *(short8*)(outp + (size_t)(m0 + r) * 256 + g2 * 8) = vv;
    }
  }
}

// ---------------- score: s[n][h][l] = ((act ⊙ g) @ Wa + ba) * SCALE ----------------
template <bool GATE>
__global__ __launch_bounds__(256) void score_k(const u16* act, const float* gate,
                                               const float* Wa, const float* ba, float* sout) {
  __shared__ float Ws[256][8];
  __shared__ float gs[256];
  int tid = threadIdx.x;
  for (int i = tid; i < 2048; i += 256) ((float*)Ws)[i] = Wa[i];
  if (GATE) gs[tid] = gate[(blockIdx.x >> 5) * 256 + tid];
  __syncthreads();
  int wv = tid >> 6, lane = tid & 63;
  int rl = lane >> 2, qq = lane & 3;
  for (int r0 = wv * 16; r0 < 128; r0 += 64) {
    int row = blockIdx.x * 128 + r0 + rl;
    const u16* ap = act + (size_t)row * 256 + qq * 64;
    float acc[8] = {0, 0, 0, 0, 0, 0, 0, 0};
#pragma unroll
    for (int ch = 0; ch < 8; ++ch) {
      short8 v = *(const short8*)(ap + ch * 8);
#pragma unroll
      for (int e = 0; e < 8; ++e) {
        int c = qq * 64 + ch * 8 + e;
        float x = b2f(((u16*)&v)[e]);
        if (GATE) x *= gs[c];
#pragma unroll
        for (int h = 0; h < 8; ++h) acc[h] += x * Ws[c][h];
      }
    }
#pragma unroll
    for (int h = 0; h < 8; ++h) {
      acc[h] += __shfl_xor(acc[h], 1);
      acc[h] += __shfl_xor(acc[h], 2);
    }
    if (qq == 0) {
      int n = row >> 12, l = row & 4095;
#pragma unroll
      for (int h = 0; h < 8; ++h)
        sout[(((size_t)n * 8 + h) << 12) + l] = (acc[h] + ba[h]) * SCALE_C;
    }
  }
}

// ---------------- pooled softmax, phase A: per (n,h,half-of-L) partials ----------
__global__ __launch_bounds__(256) void pool_a(const float* score, const u16* act,
                                              float* pmax, float* psum, float* pacc) {
  __shared__ float p[2048];
  __shared__ float red[8];
  __shared__ float wsum[4][32];
  int nh = blockIdx.x >> 1, half = blockIdx.x & 1;
  int n = nh >> 3, h = nh & 7;
  const float* s = score + ((size_t)nh << 12) + (half << 11);
  int tid = threadIdx.x;
  float v[8];
  float lmax = -3.0e38f;
#pragma unroll
  for (int i = 0; i < 8; ++i) { v[i] = s[i * 256 + tid]; lmax = fmaxf(lmax, v[i]); }
  for (int o = 32; o; o >>= 1) lmax = fmaxf(lmax, __shfl_xor(lmax, o));
  if ((tid & 63) == 0) red[tid >> 6] = lmax;
  __syncthreads();
  float m = fmaxf(fmaxf(red[0], red[1]), fmaxf(red[2], red[3]));
  float ls = 0.f;
#pragma unroll
  for (int i = 0; i < 8; ++i) { float e = __expf(v[i] - m); p[i * 256 + tid] = e; ls += e; }
  for (int o = 32; o; o >>= 1) ls += __shfl_xor(ls, o);
  if ((tid & 63) == 0) red[4 + (tid >> 6)] = ls;
  __syncthreads();
  float S = red[4] + red[5] + red[6] + red[7];
  float acc[32];
#pragma unroll
  for (int d = 0; d < 32; ++d) acc[d] = 0.f;
  const u16* ap = act + ((size_t)(n * 4096 + half * 2048)) * 256 + h * 32;
  for (int it = 0; it < 8; ++it) {
    int row = it * 256 + tid;
    float wgt = p[row];
    const u16* rp = ap + (size_t)row * 256;
#pragma unroll
    for (int ch = 0; ch < 4; ++ch) {
      short8 x = *(const short8*)(rp + ch * 8);
#pragma unroll
      for (int e = 0; e < 8; ++e) acc[ch * 8 + e] += wgt * b2f(((u16*)&x)[e]);
    }
  }
#pragma unroll
  for (int d = 0; d < 32; ++d)
    for (int o = 32; o; o >>= 1) acc[d] += __shfl_xor(acc[d], o);
  __syncthreads();
  if ((tid & 63) == 0)
#pragma unroll
    for (int d = 0; d < 32; ++d) wsum[tid >> 6][d] = acc[d];
  __syncthreads();
  if (tid < 32)
    pacc[(size_t)blockIdx.x * 32 + tid] =
        wsum[0][tid] + wsum[1][tid] + wsum[2][tid] + wsum[3][tid];
  if (tid == 0) { pmax[blockIdx.x] = m; psum[blockIdx.x] = S; }
}

// ---------------- pooled softmax, phase B: combine halves ----------------
__global__ void pool_b(const float* pmax, const float* psum, const float* pacc,
                       float* pooled) {
  int nh = blockIdx.x * 2 + (threadIdx.x >> 5);
  int d = threadIdx.x & 31;
  float m0 = pmax[nh * 2], m1 = pmax[nh * 2 + 1];
  float m = fmaxf(m0, m1);
  float w0 = __expf(m0 - m), w1 = __expf(m1 - m);
  float S = psum[nh * 2] * w0 + psum[nh * 2 + 1] * w1;
  float a = pacc[(size_t)(nh * 2) * 32 + d] * w0 + pacc[(size_t)(nh * 2 + 1) * 32 + d] * w1;
  int n = nh >> 3, h = nh & 7;
  pooled[(n << 8) + h * 32 + d] = a / S;
}

// ---------------- launch ----------------
extern "C" void kernel_launch(void* const* d_in, const int* in_sizes, int n_in,
                              void* d_out, int out_size, void* d_ws, size_t ws_size,
                              hipStream_t stream) {
  const float* x_q = (const float*)d_in[0];
  const float* x_kv = (const float*)d_in[1];
  const float* Wq = (const float*)d_in[2];
  const float* bq = (const float*)d_in[3];
  const float* Wqa = (const float*)d_in[4];
  const float* bqa = (const float*)d_in[5];
  const float* Wk = (const float*)d_in[6];
  const float* bk = (const float*)d_in[7];
  const float* Wka = (const float*)d_in[8];
  const float* bka = (const float*)d_in[9];
  const float* Wv = (const float*)d_in[10];
  const float* bv = (const float*)d_in[11];
  const float* Wt = (const float*)d_in[12];
  const float* bt = (const float*)d_in[13];
  const float* Wo = (const float*)d_in[14];
  const float* bo = (const float*)d_in[15];

  char* w = (char*)d_ws;
  size_t off = 0;
  u16* q_ws = (u16*)(w + off); off += (size_t)65536 * 256 * 2;   // 32MB
  u16* k_ws = (u16*)(w + off); off += (size_t)65536 * 256 * 2;   // 32MB
  u16* v_ws = (u16*)(w + off); off += (size_t)65536 * 256 * 2;   // 32MB
  float* score = (float*)(w + off); off += (size_t)16 * 8 * 4096 * 4;  // 2MB shared q/k
  float* pq = (float*)(w + off); off += 16 * 256 * 4;
  float* pk = (float*)(w + off); off += 16 * 256 * 4;
  float* pmax = (float*)(w + off); off += 256 * 4;
  float* psum = (float*)(w + off); off += 256 * 4;
  float* pacc = (float*)(w + off); off += 256 * 32 * 4;
  u16* wqT = (u16*)(w + off); off += 256 * 256 * 2;
  u16* wkvT = (u16*)(w + off); off += 512 * 256 * 2;
  u16* woT = (u16*)(w + off); off += 256 * 256 * 2;
  float* wtloT = (float*)(w + off); off += 256 * 256 * 4;
  float* btlo = (float*)(w + off); off += 256 * 4;
  float* bkv = (float*)(w + off); off += 512 * 4;
  u16* B5 = (u16*)(w + off); off += (size_t)16 * 256 * 512 * 2;  // 4MB
  if (ws_size < off) return;

  prep01<<<256, 256, 0, stream>>>(Wq, Wk, Wv, Wo, bk, bv, Wt, bt, bo,
                                  wqT, wkvT, woT, bkv, wtloT, btlo);

  // G1: q = x_q @ Wq + bq -> q_ws
  gemmW<0><<<1024, 256, 0, stream>>>(x_q, nullptr, nullptr, wqT, bq,
                                     q_ws, nullptr, nullptr);
  score_k<false><<<512, 256, 0, stream>>>(q_ws, nullptr, Wqa, bqa, score);
  pool_a<<<256, 256, 0, stream>>>(score, q_ws, pmax, psum, pacc);
  pool_b<<<64, 64, 0, stream>>>(pmax, psum, pacc, pq);

  // G2: [k|v] = x_kv @ [Wk|Wv] + [bk|bv] -> k_ws, v_ws
  gemmW<1><<<2048, 256, 0, stream>>>(x_kv, nullptr, nullptr, wkvT, bkv,
                                     k_ws, v_ws, nullptr);
  score_k<true><<<512, 256, 0, stream>>>(k_ws, pq, Wka, bka, score);
  pool_a<<<256, 256, 0, stream>>>(score, k_ws, pmax, psum, pacc);
  pool_b<<<64, 64, 0, stream>>>(pmax, psum, pacc, pk);

  // per-n B5 = [diag(pk)*Wtlo ; Wo]  ([n][j][512])
  prep2<<<16 * 256, 256, 0, stream>>>(pk, wtloT, woT, B5);

  // G3: out = v @ B5_lo + q @ Wo + btlo  (dual-A bf16, K=512, fp32 out)
  gemmW<2><<<1024, 256, 0, stream>>>(nullptr, v_ws, q_ws, B5, btlo,
                                     nullptr, nullptr, (float*)d_out);
}

// Round 10
// 242.105 us; speedup vs baseline: 1.1721x; 1.1721x over previous
//
#include <hip/hip_runtime.h>
#include <hip/hip_bf16.h>

typedef short short8 __attribute__((ext_vector_type(8)));
typedef float f32x4 __attribute__((ext_vector_type(4)));
typedef unsigned short u16;

#define SCALE_C 0.17677669529663687f

__device__ __forceinline__ u16 f2b(float f) {
  union { float f; unsigned int u; } v; v.f = f;
  unsigned int u = v.u;
  return (u16)((u + 0x7FFFu + ((u >> 16) & 1u)) >> 16);
}
__device__ __forceinline__ float b2f(u16 b) {
  union { unsigned int u; float f; } v; v.u = ((unsigned int)b) << 16; return v.f;
}
__device__ __forceinline__ unsigned int cvtpk(float lo, float hi) {
  unsigned int r;
  asm("v_cvt_pk_bf16_f32 %0, %1, %2" : "=v"(r) : "v"(lo), "v"(hi));
  return r;
}
__device__ __forceinline__ void glds16(const void* g, void* l) {
  __builtin_amdgcn_global_load_lds(
      (const __attribute__((address_space(1))) unsigned int*)g,
      (__attribute__((address_space(3))) unsigned int*)l, 16, 0, 0);
}

// ---------------- prep (fused): weight transposes + Wtlo + biases ----------------
__global__ void prep01(const float* Wq, const float* Wk, const float* Wv, const float* Wo,
                       const float* bk, const float* bv, const float* Wt,
                       const float* bt, const float* bo,
                       u16* wqT, u16* wkvT, u16* woT, float* bkv,
                       float* wtloT, float* btlo) {
  int j = blockIdx.x, t = threadIdx.x;
  wqT[j * 256 + t] = f2b(Wq[t * 256 + j]);
  wkvT[j * 256 + t] = f2b(Wk[t * 256 + j]);
  wkvT[(256 + j) * 256 + t] = f2b(Wv[t * 256 + j]);
  woT[j * 256 + t] = f2b(Wo[t * 256 + j]);
  if (t == 0) { bkv[j] = bk[j]; bkv[256 + j] = bv[j]; }
  __shared__ float woj[256];
  woj[t] = Wo[t * 256 + j];
  __syncthreads();
  float s = 0.f;
  const float* wr = Wt + t * 256;
#pragma unroll 8
  for (int u = 0; u < 256; ++u) s += wr[u] * woj[u];
  wtloT[j * 256 + t] = s;  // = Wtlo[t][j]
  if (t == 0) {
    float b = bo[j];
    for (int u = 0; u < 256; ++u) b += bt[u] * woj[u];
    btlo[j] = b;
  }
}

__global__ void prep2(const float* pk, const float* wtloT, const u16* woT, u16* B5) {
  int n = blockIdx.x >> 8, j = blockIdx.x & 255, t = threadIdx.x;
  u16* r = B5 + ((size_t)(n * 256 + j)) * 512;
  r[t] = f2b(pk[n * 256 + t] * wtloT[j * 256 + t]);
  r[256 + t] = woT[j * 256 + t];
}

// ---------------- B-resident GEMM: weights live in LDS, barrier-free main loop ----
// Block = 512 threads (8 waves), LDS = full B^T panel (128KB), loaded once via
// glds16 with source-side inverse XOR swizzle, then ONE barrier. Each wave then
// independently computes a 32-row x (COLT*16)-col strip: A straight from global
// (fp32 + v_cvt_pk for MODE 0/1, bf16 for MODE 2), B frags from swizzled LDS
// (2-way bank aliasing = free), accumulate, store. No K-loop barriers at all.
// MODE 0: q = x_q @ Wq + bq            grid 256   (B = wqT, 256x256)
// MODE 1: [k|v] = x_kv @ [Wk|Wv]+[...] grid 512   (B = wkvT col-half per block)
// MODE 2: out = [v;q] @ B5(n) + btlo   grid 512   (B = B5 slab col-half, K=512)
template <int MODE>
__global__ __launch_bounds__(512, 2) void gemmB(
    const float* Xf, const u16* Aq, const u16* Av, const u16* BT,
    const float* bias, u16* outk, u16* outv, float* outf) {
  __shared__ __align__(16) u16 Bs[65536];        // 128KB
  constexpr int GPR = (MODE == 2) ? 64 : 32;     // 16B granules per LDS row
  constexpr int HM = (MODE == 2) ? 0x38 : 0x18;  // swizzle high-bit mask
  constexpr int ROWB = GPR * 16;                 // bytes per LDS row
  constexpr int COLT = (MODE == 2) ? 8 : 16;     // 16-col tiles per strip
  int bid = blockIdx.x, tid = threadIdx.x;
  int lane = tid & 63, w = tid >> 6;
  int rla = lane & 15, hi = lane >> 4;
  int blkm, h = 0, n = 0;
  const u16* Bsrc;
  const float* bs;
  u16* outp = nullptr;
  if constexpr (MODE == 0) {
    blkm = bid; Bsrc = BT; bs = bias; outp = outk;
  } else if constexpr (MODE == 1) {
    h = bid & 1; blkm = bid >> 1;
    Bsrc = BT + h * 65536; bs = bias + h * 256; outp = h ? outv : outk;
  } else {
    blkm = bid & 15; h = (bid >> 4) & 1; n = bid >> 5;
    Bsrc = BT + (size_t)n * 131072 + h * 128 * 512;
    bs = bias + h * 128;
  }

  // ---- one-time cooperative B load: 8192 granules, 16 per thread ----
#pragma unroll
  for (int p = 0; p < 16; ++p) {
    int gi = p * 512 + tid;
    int r = gi / GPR, g = gi % GPR;
    int gs = (g & HM) | ((g & 7) ^ (r & 7));
    glds16(Bsrc + (size_t)r * (GPR * 8) + gs * 8, (char*)Bs + gi * 16);
  }
  __syncthreads();  // drains glds; the ONLY barrier

  int m0 = ((MODE == 2) ? n * 4096 : 0) + blkm * 256 + w * 32;

  f32x4 acc[2][COLT];
#pragma unroll
  for (int i = 0; i < 2; ++i)
#pragma unroll
    for (int j = 0; j < COLT; ++j) acc[i][j] = (f32x4){0.f, 0.f, 0.f, 0.f};

  if constexpr (MODE != 2) {
    // A: fp32 straight from global, cvt_pk to bf16 fragments
    short8 af[2][8];
#pragma unroll
    for (int i = 0; i < 2; ++i)
#pragma unroll
      for (int kc = 0; kc < 8; ++kc) {
        int row = m0 + i * 16 + rla;
        const float* pa = Xf + (size_t)row * 256 + kc * 32 + hi * 8;
        f32x4 x = *(const f32x4*)pa;
        f32x4 y = *(const f32x4*)(pa + 4);
        unsigned int* op = (unsigned int*)&af[i][kc];
        op[0] = cvtpk(x[0], x[1]); op[1] = cvtpk(x[2], x[3]);
        op[2] = cvtpk(y[0], y[1]); op[3] = cvtpk(y[2], y[3]);
      }
#pragma unroll
    for (int kc = 0; kc < 8; ++kc)
#pragma unroll
      for (int j = 0; j < COLT; ++j) {
        int rb = j * 16 + rla;
        int g = kc * 4 + hi;
        int lg = (g & HM) | ((g & 7) ^ (rb & 7));
        short8 bf = *(const short8*)((char*)Bs + rb * ROWB + lg * 16);
        acc[0][j] = __builtin_amdgcn_mfma_f32_16x16x32_bf16(af[0][kc], bf, acc[0][j], 0, 0, 0);
        acc[1][j] = __builtin_amdgcn_mfma_f32_16x16x32_bf16(af[1][kc], bf, acc[1][j], 0, 0, 0);
      }
  } else {
    // K=512 dual-A: half 0 = v (B k-chunks 0..7), half 1 = q (8..15)
#pragma unroll
    for (int half = 0; half < 2; ++half) {
      const u16* Ak = half ? Aq : Av;
      short8 af[2][8];
#pragma unroll
      for (int i = 0; i < 2; ++i)
#pragma unroll
        for (int kc = 0; kc < 8; ++kc) {
          int row = m0 + i * 16 + rla;
          af[i][kc] = *(const short8*)(Ak + (size_t)row * 256 + kc * 32 + hi * 8);
        }
#pragma unroll
      for (int kc = 0; kc < 8; ++kc)
#pragma unroll
        for (int j = 0; j < COLT; ++j) {
          int rb = j * 16 + rla;
          int g = (half * 8 + kc) * 4 + hi;
          int lg = (g & HM) | ((g & 7) ^ (rb & 7));
          short8 bf = *(const short8*)((char*)Bs + rb * ROWB + lg * 16);
          acc[0][j] = __builtin_amdgcn_mfma_f32_16x16x32_bf16(af[0][kc], bf, acc[0][j], 0, 0, 0);
          acc[1][j] = __builtin_amdgcn_mfma_f32_16x16x32_bf16(af[1][kc], bf, acc[1][j], 0, 0, 0);
        }
    }
  }

  // ---- epilogue ----
  if constexpr (MODE == 2) {
#pragma unroll
    for (int j = 0; j < COLT; ++j) {
      int col = h * 128 + j * 16 + rla;
      float bb = bs[j * 16 + rla];
#pragma unroll
      for (int i = 0; i < 2; ++i)
#pragma unroll
        for (int e = 0; e < 4; ++e) {
          int row = m0 + i * 16 + hi * 4 + e;
          outf[(size_t)row * 256 + col] = acc[i][j][e] + bb;
        }
    }
  } else {
#pragma unroll
    for (int j = 0; j < COLT; ++j) {
      int col = j * 16 + rla;
      float bb = bs[col];
#pragma unroll
      for (int i = 0; i < 2; ++i)
#pragma unroll
        for (int e = 0; e < 4; ++e) {
          int row = m0 + i * 16 + hi * 4 + e;
          outp[(size_t)row * 256 + col] = f2b(acc[i][j][e] + bb);
        }
    }
  }
}

// ---------------- score: s[n][h][l] = ((act ⊙ g) @ Wa + ba) * SCALE ----------------
template <bool GATE>
__global__ __launch_bounds__(256) void score_k(const u16* act, const float* gate,
                                               const float* Wa, const float* ba, float* sout) {
  __shared__ float Ws[256][8];
  __shared__ float gs[256];
  int tid = threadIdx.x;
  for (int i = tid; i < 2048; i += 256) ((float*)Ws)[i] = Wa[i];
  if (GATE) gs[tid] = gate[(blockIdx.x >> 5) * 256 + tid];
  __syncthreads();
  int wv = tid >> 6, lane = tid & 63;
  int rl = lane >> 2, qq = lane & 3;
  for (int r0 = wv * 16; r0 < 128; r0 += 64) {
    int row = blockIdx.x * 128 + r0 + rl;
    const u16* ap = act + (size_t)row * 256 + qq * 64;
    float acc[8] = {0, 0, 0, 0, 0, 0, 0, 0};
#pragma unroll
    for (int ch = 0; ch < 8; ++ch) {
      short8 v = *(const short8*)(ap + ch * 8);
#pragma unroll
      for (int e = 0; e < 8; ++e) {
        int c = qq * 64 + ch * 8 + e;
        float x = b2f(((u16*)&v)[e]);
        if (GATE) x *= gs[c];
#pragma unroll
        for (int h = 0; h < 8; ++h) acc[h] += x * Ws[c][h];
      }
    }
#pragma unroll
    for (int h = 0; h < 8; ++h) {
      acc[h] += __shfl_xor(acc[h], 1);
      acc[h] += __shfl_xor(acc[h], 2);
    }
    if (qq == 0) {
      int n = row >> 12, l = row & 4095;
#pragma unroll
      for (int h = 0; h < 8; ++h)
        sout[(((size_t)n * 8 + h) << 12) + l] = (acc[h] + ba[h]) * SCALE_C;
    }
  }
}

// ---------------- pooled softmax, phase A: per (n,h,half-of-L) partials ----------
__global__ __launch_bounds__(256) void pool_a(const float* score, const u16* act,
                                              float* pmax, float* psum, float* pacc) {
  __shared__ float p[2048];
  __shared__ float red[8];
  __shared__ float wsum[4][32];
  int nh = blockIdx.x >> 1, half = blockIdx.x & 1;
  int n = nh >> 3, h = nh & 7;
  const float* s = score + ((size_t)nh << 12) + (half << 11);
  int tid = threadIdx.x;
  float v[8];
  float lmax = -3.0e38f;
#pragma unroll
  for (int i = 0; i < 8; ++i) { v[i] = s[i * 256 + tid]; lmax = fmaxf(lmax, v[i]); }
  for (int o = 32; o; o >>= 1) lmax = fmaxf(lmax, __shfl_xor(lmax, o));
  if ((tid & 63) == 0) red[tid >> 6] = lmax;
  __syncthreads();
  float m = fmaxf(fmaxf(red[0], red[1]), fmaxf(red[2], red[3]));
  float ls = 0.f;
#pragma unroll
  for (int i = 0; i < 8; ++i) { float e = __expf(v[i] - m); p[i * 256 + tid] = e; ls += e; }
  for (int o = 32; o; o >>= 1) ls += __shfl_xor(ls, o);
  if ((tid & 63) == 0) red[4 + (tid >> 6)] = ls;
  __syncthreads();
  float S = red[4] + red[5] + red[6] + red[7];
  float acc[32];
#pragma unroll
  for (int d = 0; d < 32; ++d) acc[d] = 0.f;
  const u16* ap = act + ((size_t)(n * 4096 + half * 2048)) * 256 + h * 32;
  for (int it = 0; it < 8; ++it) {
    int row = it * 256 + tid;
    float wgt = p[row];
    const u16* rp = ap + (size_t)row * 256;
#pragma unroll
    for (int ch = 0; ch < 4; ++ch) {
      short8 x = *(const short8*)(rp + ch * 8);
#pragma unroll
      for (int e = 0; e < 8; ++e) acc[ch * 8 + e] += wgt * b2f(((u16*)&x)[e]);
    }
  }
#pragma unroll
  for (int d = 0; d < 32; ++d)
    for (int o = 32; o; o >>= 1) acc[d] += __shfl_xor(acc[d], o);
  __syncthreads();
  if ((tid & 63) == 0)
#pragma unroll
    for (int d = 0; d < 32; ++d) wsum[tid >> 6][d] = acc[d];
  __syncthreads();
  if (tid < 32)
    pacc[(size_t)blockIdx.x * 32 + tid] =
        wsum[0][tid] + wsum[1][tid] + wsum[2][tid] + wsum[3][tid];
  if (tid == 0) { pmax[blockIdx.x] = m; psum[blockIdx.x] = S; }
}

// ---------------- pooled softmax, phase B: combine halves ----------------
__global__ void pool_b(const float* pmax, const float* psum, const float* pacc,
                       float* pooled) {
  int nh = blockIdx.x * 2 + (threadIdx.x >> 5);
  int d = threadIdx.x & 31;
  float m0 = pmax[nh * 2], m1 = pmax[nh * 2 + 1];
  float m = fmaxf(m0, m1);
  float w0 = __expf(m0 - m), w1 = __expf(m1 - m);
  float S = psum[nh * 2] * w0 + psum[nh * 2 + 1] * w1;
  float a = pacc[(size_t)(nh * 2) * 32 + d] * w0 + pacc[(size_t)(nh * 2 + 1) * 32 + d] * w1;
  int n = nh >> 3, h = nh & 7;
  pooled[(n << 8) + h * 32 + d] = a / S;
}

// ---------------- launch ----------------
extern "C" void kernel_launch(void* const* d_in, const int* in_sizes, int n_in,
                              void* d_out, int out_size, void* d_ws, size_t ws_size,
                              hipStream_t stream) {
  const float* x_q = (const float*)d_in[0];
  const float* x_kv = (const float*)d_in[1];
  const float* Wq = (const float*)d_in[2];
  const float* bq = (const float*)d_in[3];
  const float* Wqa = (const float*)d_in[4];
  const float* bqa = (const float*)d_in[5];
  const float* Wk = (const float*)d_in[6];
  const float* bk = (const float*)d_in[7];
  const float* Wka = (const float*)d_in[8];
  const float* bka = (const float*)d_in[9];
  const float* Wv = (const float*)d_in[10];
  const float* bv = (const float*)d_in[11];
  const float* Wt = (const float*)d_in[12];
  const float* bt = (const float*)d_in[13];
  const float* Wo = (const float*)d_in[14];
  const float* bo = (const float*)d_in[15];

  char* w = (char*)d_ws;
  size_t off = 0;
  u16* q_ws = (u16*)(w + off); off += (size_t)65536 * 256 * 2;   // 32MB
  u16* k_ws = (u16*)(w + off); off += (size_t)65536 * 256 * 2;   // 32MB
  u16* v_ws = (u16*)(w + off); off += (size_t)65536 * 256 * 2;   // 32MB
  float* score = (float*)(w + off); off += (size_t)16 * 8 * 4096 * 4;  // 2MB shared q/k
  float* pq = (float*)(w + off); off += 16 * 256 * 4;
  float* pk = (float*)(w + off); off += 16 * 256 * 4;
  float* pmax = (float*)(w + off); off += 256 * 4;
  float* psum = (float*)(w + off); off += 256 * 4;
  float* pacc = (float*)(w + off); off += 256 * 32 * 4;
  u16* wqT = (u16*)(w + off); off += 256 * 256 * 2;
  u16* wkvT = (u16*)(w + off); off += 512 * 256 * 2;
  u16* woT = (u16*)(w + off); off += 256 * 256 * 2;
  float* wtloT = (float*)(w + off); off += 256 * 256 * 4;
  float* btlo = (float*)(w + off); off += 256 * 4;
  float* bkv = (float*)(w + off); off += 512 * 4;
  u16* B5 = (u16*)(w + off); off += (size_t)16 * 256 * 512 * 2;  // 4MB
  if (ws_size < off) return;

  prep01<<<256, 256, 0, stream>>>(Wq, Wk, Wv, Wo, bk, bv, Wt, bt, bo,
                                  wqT, wkvT, woT, bkv, wtloT, btlo);

  // G1: q = x_q @ Wq + bq -> q_ws
  gemmB<0><<<256, 512, 0, stream>>>(x_q, nullptr, nullptr, wqT, bq,
                                    q_ws, nullptr, nullptr);
  score_k<false><<<512, 256, 0, stream>>>(q_ws, nullptr, Wqa, bqa, score);
  pool_a<<<256, 256, 0, stream>>>(score, q_ws, pmax, psum, pacc);
  pool_b<<<64, 64, 0, stream>>>(pmax, psum, pacc, pq);

  // G2: [k|v] = x_kv @ [Wk|Wv] + [bk|bv] -> k_ws, v_ws
  gemmB<1><<<512, 512, 0, stream>>>(x_kv, nullptr, nullptr, wkvT, bkv,
                                    k_ws, v_ws, nullptr);
  score_k<true><<<512, 256, 0, stream>>>(k_ws, pq, Wka, bka, score);
  pool_a<<<256, 256, 0, stream>>>(score, k_ws, pmax, psum, pacc);
  pool_b<<<64, 64, 0, stream>>>(pmax, psum, pacc, pk);

  // per-n B5 = [diag(pk)*Wtlo ; Wo]  ([n][j][512])
  prep2<<<16 * 256, 256, 0, stream>>>(pk, wtloT, woT, B5);

  // G3: out = v @ B5_lo + q @ Wo + btlo  (dual-A bf16, K=512, fp32 out)
  gemmB<2><<<512, 512, 0, stream>>>(nullptr, q_ws, v_ws, B5, btlo,
                                    nullptr, nullptr, (float*)d_out);
}